// Round 7
// baseline (113.534 us; speedup 1.0000x reference)
//
#include <hip/hip_runtime.h>

#define D_FEAT 64

// Kernel 1: row_ptr via edge-parallel boundary scatter (edge_dst sorted).
// rp[v] = first edge index with dst >= v, v in [0, N]. O(E) coalesced.
__global__ __launch_bounds__(256) void build_rowptr_scatter(
    const int* __restrict__ edge_dst, int* __restrict__ rp,
    int n_edges, int n_nodes) {
  const int e = blockIdx.x * blockDim.x + threadIdx.x;
  if (e > n_edges) return;
  const int d0 = (e == 0) ? -1 : edge_dst[e - 1];
  const int d1 = (e == n_edges) ? n_nodes : edge_dst[e];
  for (int v = d0 + 1; v <= d1; ++v) rp[v] = e;
}

// Kernel 2: TWO destination nodes per wave (avg degree ~25 -> ~50 edges,
// usually one 64-edge batch). Amortizes the serial per-wave prologue
// (rp load -> esrc/ew load) over 2x the edges and halves occupancy-rounds.
// lane = 16*edge_slot + float4_idx; one dwordx4 fetches 4 feat rows.
// Slots belonging to node A vs B are separated by a weight select:
// wA = (edge_idx < r1) ? w : 0 ; wB = w - wA. Dual accumulators.
__global__ __launch_bounds__(256) void gcn_gather4x2(
    const float* __restrict__ feat,
    const float* __restrict__ ew,
    const int* __restrict__ esrc,
    const int* __restrict__ rp,
    float* __restrict__ out, int n_nodes) {
  const int wave = (blockIdx.x * blockDim.x + threadIdx.x) >> 6;
  const int lane = threadIdx.x & 63;
  const int vA = wave * 2;
  if (vA >= n_nodes) return;
  const bool hasB = (vA + 1) < n_nodes;

  const int sub = lane >> 4;   // edge slot 0..3
  const int fl  = lane & 15;   // float4 index within the 64-float row

  const int r0 = rp[vA];
  const int r1 = rp[vA + 1];
  const int r2 = hasB ? rp[vA + 2] : r1;

  float4 aA = {0.f, 0.f, 0.f, 0.f};
  float4 aB = {0.f, 0.f, 0.f, 0.f};

  const float4* feat4 = (const float4*)feat;

  for (int base = r0; base < r2; base += 64) {
    const int n = min(64, r2 - base);
    int   s = 0;
    float w = 0.0f;
    if (lane < n) {
      s = esrc[base + lane];
      w = ew[base + lane];   // lanes >= n keep w = 0 -> contribute nothing
    }
    // i <= 48, so max shfl index = 48 + 12 + 3 = 63.
    for (int i = 0; i < n; i += 16) {
      const int   s0 = __shfl(s, i + sub);
      const float w0 = __shfl(w, i + sub);
      const int   s1 = __shfl(s, i + 4 + sub);
      const float w1 = __shfl(w, i + 4 + sub);
      const int   s2 = __shfl(s, i + 8 + sub);
      const float w2 = __shfl(w, i + 8 + sub);
      const int   s3 = __shfl(s, i + 12 + sub);
      const float w3 = __shfl(w, i + 12 + sub);

      const float4 q0 = feat4[(size_t)s0 * 16 + fl];
      const float4 q1 = feat4[(size_t)s1 * 16 + fl];
      const float4 q2 = feat4[(size_t)s2 * 16 + fl];
      const float4 q3 = feat4[(size_t)s3 * 16 + fl];

      const int i0 = base + i + sub;
      const int i1 = i0 + 4;
      const int i2 = i0 + 8;
      const int i3 = i0 + 12;
      const float w0A = (i0 < r1) ? w0 : 0.f; const float w0B = w0 - w0A;
      const float w1A = (i1 < r1) ? w1 : 0.f; const float w1B = w1 - w1A;
      const float w2A = (i2 < r1) ? w2 : 0.f; const float w2B = w2 - w2A;
      const float w3A = (i3 < r1) ? w3 : 0.f; const float w3B = w3 - w3A;

      aA.x = fmaf(q0.x, w0A, aA.x); aA.y = fmaf(q0.y, w0A, aA.y);
      aA.z = fmaf(q0.z, w0A, aA.z); aA.w = fmaf(q0.w, w0A, aA.w);
      aB.x = fmaf(q0.x, w0B, aB.x); aB.y = fmaf(q0.y, w0B, aB.y);
      aB.z = fmaf(q0.z, w0B, aB.z); aB.w = fmaf(q0.w, w0B, aB.w);

      aA.x = fmaf(q1.x, w1A, aA.x); aA.y = fmaf(q1.y, w1A, aA.y);
      aA.z = fmaf(q1.z, w1A, aA.z); aA.w = fmaf(q1.w, w1A, aA.w);
      aB.x = fmaf(q1.x, w1B, aB.x); aB.y = fmaf(q1.y, w1B, aB.y);
      aB.z = fmaf(q1.z, w1B, aB.z); aB.w = fmaf(q1.w, w1B, aB.w);

      aA.x = fmaf(q2.x, w2A, aA.x); aA.y = fmaf(q2.y, w2A, aA.y);
      aA.z = fmaf(q2.z, w2A, aA.z); aA.w = fmaf(q2.w, w2A, aA.w);
      aB.x = fmaf(q2.x, w2B, aB.x); aB.y = fmaf(q2.y, w2B, aB.y);
      aB.z = fmaf(q2.z, w2B, aB.z); aB.w = fmaf(q2.w, w2B, aB.w);

      aA.x = fmaf(q3.x, w3A, aA.x); aA.y = fmaf(q3.y, w3A, aA.y);
      aA.z = fmaf(q3.z, w3A, aA.z); aA.w = fmaf(q3.w, w3A, aA.w);
      aB.x = fmaf(q3.x, w3B, aB.x); aB.y = fmaf(q3.y, w3B, aB.y);
      aB.z = fmaf(q3.z, w3B, aB.z); aB.w = fmaf(q3.w, w3B, aB.w);
    }
  }

  // Reduce 4 edge-slot partials; after xor16+xor32 every lane holds the sum.
  aA.x += __shfl_xor(aA.x, 16); aA.y += __shfl_xor(aA.y, 16);
  aA.z += __shfl_xor(aA.z, 16); aA.w += __shfl_xor(aA.w, 16);
  aA.x += __shfl_xor(aA.x, 32); aA.y += __shfl_xor(aA.y, 32);
  aA.z += __shfl_xor(aA.z, 32); aA.w += __shfl_xor(aA.w, 32);

  aB.x += __shfl_xor(aB.x, 16); aB.y += __shfl_xor(aB.y, 16);
  aB.z += __shfl_xor(aB.z, 16); aB.w += __shfl_xor(aB.w, 16);
  aB.x += __shfl_xor(aB.x, 32); aB.y += __shfl_xor(aB.y, 32);
  aB.z += __shfl_xor(aB.z, 32); aB.w += __shfl_xor(aB.w, 32);

  if (lane < 16) {
    ((float4*)(out + (size_t)vA * D_FEAT))[fl] = aA;
  } else if (lane < 32 && hasB) {
    ((float4*)(out + (size_t)(vA + 1) * D_FEAT))[fl] = aB;
  }
}

extern "C" void kernel_launch(void* const* d_in, const int* in_sizes, int n_in,
                              void* d_out, int out_size, void* d_ws, size_t ws_size,
                              hipStream_t stream) {
  const float* feat        = (const float*)d_in[0];
  const float* edge_weight = (const float*)d_in[1];
  const int*   edge_src    = (const int*)d_in[2];
  const int*   edge_dst    = (const int*)d_in[3];
  float* out = (float*)d_out;

  const int n_edges = in_sizes[1];            // E = 1,250,000
  const int n_nodes = out_size / D_FEAT;      // N = 50,000

  int* rp = (int*)d_ws;                       // (N+1) ints in scratch

  const int bp_threads = n_edges + 1;
  build_rowptr_scatter<<<(bp_threads + 255) / 256, 256, 0, stream>>>(
      edge_dst, rp, n_edges, n_nodes);

  const int n_waves = (n_nodes + 1) / 2;      // two nodes per wave
  const long total_threads = (long)n_waves * 64;
  gcn_gather4x2<<<(int)((total_threads + 255) / 256), 256, 0, stream>>>(
      feat, edge_weight, edge_src, rp, out, n_nodes);
}